// Round 15
// baseline (488.025 us; speedup 1.0000x reference)
//
#include <hip/hip_runtime.h>

typedef short short8 __attribute__((ext_vector_type(8)));
typedef float f32x4 __attribute__((ext_vector_type(4)));

#define DIMS   256
#define KCODES 8192
#define NTOK   32768
#define BM     32          // tokens per block (16 per wave x 2 groups)
#define BN     64          // codes per tile = 4 stripes of 16
#define NTILES 128
#define MARGIN 0.75f       // ~18 sigma of bf16 score error (sigma ~0.04)
#define CAP    3072        // 96 candidates/token

__device__ __forceinline__ unsigned short f2bf(float f) {
    unsigned u = __builtin_bit_cast(unsigned, f);
    unsigned r = (u + 0x7FFFu + ((u >> 16) & 1u)) >> 16;   // RNE
    return (unsigned short)r;
}
__device__ __forceinline__ unsigned fenc(float f) {        // order-preserving float->uint (cold path)
    unsigned u = __builtin_bit_cast(unsigned, f);
    return ((int)u >= 0) ? (u | 0x80000000u) : ~u;
}

// prep: c2[k] = ||cb[k]||^2 (fp32), and codebook -> bf16 in MFMA-FRAGMENT-MAJOR layout:
//   cbbf elem offset g*4096 + kk*512 + lane*8  <=  cb row (g*16 + (lane&15)), dims [(lane>>4)*8 + kk*32, +8)
__global__ __launch_bounds__(256) void prep_kernel(const float* __restrict__ cb,
                                                   float* __restrict__ c2,
                                                   unsigned short* __restrict__ cbbf,
                                                   int do_conv) {
    const int g    = blockIdx.x * 4 + (threadIdx.x >> 6);   // group of 16 codes
    const int lane = threadIdx.x & 63;
    const int l15  = lane & 15;
    const int quad = lane >> 4;
    const float* rp = cb + (size_t)(g * 16 + l15) * DIMS + quad * 8;
    float ss = 0.f;
#pragma unroll
    for (int kk = 0; kk < 8; kk++) {
        float4 v0 = *(const float4*)(rp + kk * 32);
        float4 v1 = *(const float4*)(rp + kk * 32 + 4);
        ss += v0.x * v0.x + v0.y * v0.y + v0.z * v0.z + v0.w * v0.w
            + v1.x * v1.x + v1.y * v1.y + v1.z * v1.z + v1.w * v1.w;
        if (do_conv) {
            short8 s;
            s[0] = f2bf(v0.x); s[1] = f2bf(v0.y); s[2] = f2bf(v0.z); s[3] = f2bf(v0.w);
            s[4] = f2bf(v1.x); s[5] = f2bf(v1.y); s[6] = f2bf(v1.z); s[7] = f2bf(v1.w);
            *(short8*)(cbbf + (size_t)g * 4096 + kk * 512 + lane * 8) = s;
        }
    }
    ss += __shfl_xor(ss, 16);
    ss += __shfl_xor(ss, 32);
    if (quad == 0) c2[g * 16 + l15] = ss;
}

template <bool WSBF>
__global__ __launch_bounds__(512, 4) void vq_main(const float* __restrict__ h,
                                                  const float* __restrict__ cb,
                                                  const unsigned short* __restrict__ cbbf,
                                                  const float* __restrict__ c2g,
                                                  float* __restrict__ out_q,
                                                  float* __restrict__ out_idx) {
    // No B-tile in LDS, no main-loop barriers. Two NAMED B-register buffers ping-pong
    // across tiles: tile t computes from the buffer loaded at t-2, then reloads it for t+2
    // -> a full tile of latency slack for the 8 L2 loads, and zero scratch spill.
    __shared__ unsigned mrun[BM];                 // raw float bits (positive) running min
    __shared__ unsigned list[CAP];                // 12288 B
    __shared__ unsigned long long best64[BM];
    __shared__ int cnt;

    const int tid  = threadIdx.x;          // 0..511
    const int lane = tid & 63;
    const int wave = tid >> 6;             // 0..7
    const int l15  = lane & 15;
    const int quad = lane >> 4;
    const int wTok = wave >> 2;            // 0..1 : 16-token group
    const int wn   = wave & 3;             // 0..3 : 16-code stripe within tile
    const int tok  = wTok * 16 + l15;      // this lane's token (one per lane)
    const int tokBase = blockIdx.x * BM;

    if (tid < BM) mrun[tid] = 0x7F7FFFFFu;   // +3.4e38
    if (tid == 0) cnt = 0;

    short8 bfA[8], bfB[8];
    const char* fb = (const char*)cbbf + (size_t)wn * 8192 + (size_t)lane * 16;

#define LOADB(BF, T) do {                                                          \
        if constexpr (WSBF) {                                                      \
            const char* p_ = fb + (size_t)(T) * 32768;                             \
            _Pragma("unroll")                                                      \
            for (int n_ = 0; n_ < 8; n_++)                                         \
                BF[n_] = *(const short8*)(p_ + n_ * 1024);                         \
        } else {                                                                   \
            const float* rp_ = cb + (size_t)((T) * BN + wn * 16 + l15) * DIMS + quad * 8; \
            _Pragma("unroll")                                                      \
            for (int kk_ = 0; kk_ < 8; kk_++) {                                    \
                float4 v0_ = *(const float4*)(rp_ + kk_ * 32);                     \
                float4 v1_ = *(const float4*)(rp_ + kk_ * 32 + 4);                 \
                short8 s_;                                                         \
                s_[0] = f2bf(v0_.x); s_[1] = f2bf(v0_.y); s_[2] = f2bf(v0_.z); s_[3] = f2bf(v0_.w); \
                s_[4] = f2bf(v1_.x); s_[5] = f2bf(v1_.y); s_[6] = f2bf(v1_.z); s_[7] = f2bf(v1_.w); \
                BF[kk_] = s_;                                                      \
            }                                                                      \
        }                                                                          \
    } while (0)

    LOADB(bfA, 0);   // latency hides under afr conversion

    // ---- token fragments: wave's 16 tokens x 256 dims (bf16), B-operand layout ----
    short8 afr[8];
    {
        const float* abase = h + (size_t)(tokBase + tok) * DIMS + quad * 8;
#pragma unroll
        for (int kk = 0; kk < 8; kk++) {
            float4 v0 = *(const float4*)(abase + kk * 32);
            float4 v1 = *(const float4*)(abase + kk * 32 + 4);
            short8 s;
            s[0] = f2bf(v0.x); s[1] = f2bf(v0.y); s[2] = f2bf(v0.z); s[3] = f2bf(v0.w);
            s[4] = f2bf(v1.x); s[5] = f2bf(v1.y); s[6] = f2bf(v1.z); s[7] = f2bf(v1.w);
            afr[kk] = s;
        }
    }

    LOADB(bfB, 1);
    __syncthreads();   // mrun/cnt init visible; ONLY barrier before the rescore phase

// One tile: MFMA from BF (loaded 2 tiles ago) -> reload BF for tile TN -> epilogue.
// USETHR/UPD are compile-time in the peeled calls; PF may be a runtime bool.
#define TILE(BF, T, TN, PF, USETHR, UPD) do {                                      \
        const int t_ = (T);                                                        \
        const int cbase_ = t_ * BN + wn * 16;                                      \
        float thr_ = 0.f;                                                          \
        if (USETHR) thr_ = __builtin_bit_cast(float, mrun[tok]) + MARGIN;          \
        const float4 cc_ = *(const float4*)(c2g + cbase_ + quad * 4);              \
        f32x4 a0_ = (f32x4){0, 0, 0, 0}, a1_ = (f32x4){0, 0, 0, 0};                \
        __builtin_amdgcn_s_setprio(1);                                             \
        _Pragma("unroll")                                                          \
        for (int kk_ = 0; kk_ < 4; kk_++) {   /* split-K: 2 independent 4-chains */\
            a0_ = __builtin_amdgcn_mfma_f32_16x16x32_bf16(BF[kk_],     afr[kk_],     a0_, 0, 0, 0); \
            a1_ = __builtin_amdgcn_mfma_f32_16x16x32_bf16(BF[kk_ + 4], afr[kk_ + 4], a1_, 0, 0, 0); \
        }                                                                          \
        __builtin_amdgcn_s_setprio(0);                                             \
        if (PF) LOADB(BF, TN);   /* lands during next tile (other buffer) */       \
        const int code00_ = cbase_ + quad * 4;                                     \
        float s0_ = fmaf(-2.f, a0_[0], fmaf(-2.f, a1_[0], cc_.x));                 \
        float s1_ = fmaf(-2.f, a0_[1], fmaf(-2.f, a1_[1], cc_.y));                 \
        float s2_ = fmaf(-2.f, a0_[2], fmaf(-2.f, a1_[2], cc_.z));                 \
        float s3_ = fmaf(-2.f, a0_[3], fmaf(-2.f, a1_[3], cc_.w));                 \
        if (USETHR) {                                                              \
            const unsigned tk_ = (unsigned)(tok << 13);                            \
            if (s0_ <= thr_) { int p_ = atomicAdd(&cnt, 1); if (p_ < CAP) list[p_] = tk_ | (unsigned)(code00_ + 0); } \
            if (s1_ <= thr_) { int p_ = atomicAdd(&cnt, 1); if (p_ < CAP) list[p_] = tk_ | (unsigned)(code00_ + 1); } \
            if (s2_ <= thr_) { int p_ = atomicAdd(&cnt, 1); if (p_ < CAP) list[p_] = tk_ | (unsigned)(code00_ + 2); } \
            if (s3_ <= thr_) { int p_ = atomicAdd(&cnt, 1); if (p_ < CAP) list[p_] = tk_ | (unsigned)(code00_ + 3); } \
        }                                                                          \
        if (UPD) {                                                                 \
            float vm_ = fminf(fminf(s0_, s1_), fminf(s2_, s3_));                   \
            vm_ = fminf(vm_, __shfl_xor(vm_, 16));                                 \
            vm_ = fminf(vm_, __shfl_xor(vm_, 32));                                 \
            /* positive floats: raw bits order-preserving for atomicMin */         \
            if (quad == 0) atomicMin(&mrun[tok], __builtin_bit_cast(unsigned, vm_)); \
        }                                                                          \
    } while (0)

    // tiles 0,1 peeled (tile 0 has no thresholds yet)
    TILE(bfA, 0, 2, true, false, true);
    TILE(bfB, 1, 3, true, true,  true);
#pragma unroll 1
    for (int t2 = 1; t2 < 64; ++t2) {
        TILE(bfA, 2 * t2,     (2 * t2 + 2) & 127, true,       true, true);  // t2=63: reloads tile 0
        TILE(bfB, 2 * t2 + 1, 2 * t2 + 3,         (t2 < 63),  true, true);
    }
    // redo tile 0 with (drifted) thresholds for emission; no min update
    TILE(bfA, 0, 0, false, true, false);

    __syncthreads();   // list/cnt final

    if (tid < BM) best64[tid] = ~0ULL;
    __syncthreads();

    // ---- exact fp32 rescore of candidates ----
    int n = cnt; if (n > CAP) n = CAP;
    for (int p = wave; p < n; p += 8) {
        unsigned e = list[p];
        int tk = (int)(e >> 13), code = (int)(e & 8191);
        float4 hv = *(const float4*)(h + (size_t)(tokBase + tk) * DIMS + lane * 4);
        float4 cv = *(const float4*)(cb + (size_t)code * DIMS + lane * 4);
        float d = hv.x * cv.x + hv.y * cv.y + hv.z * cv.z + hv.w * cv.w;
#pragma unroll
        for (int m = 1; m < 64; m <<= 1) d += __shfl_xor(d, m);
        float s = c2g[code] - 2.f * d;
        if (lane == 0)
            atomicMin(&best64[tk], ((unsigned long long)fenc(s) << 32) | (unsigned)code);
    }
    __syncthreads();

    if (tid < BM)
        out_idx[tokBase + tid] = (float)(unsigned)(best64[tid] & 0xFFFFFFFFULL);
#pragma unroll
    for (int e = tid; e < BM * (DIMS / 4); e += 512) {
        int r = e >> 6, c4 = e & 63;
        int idx = (int)(unsigned)(best64[r] & 0xFFFFFFFFULL);
        float4 v = *(const float4*)(cb + (size_t)idx * DIMS + c4 * 4);
        *(float4*)(out_q + (size_t)(tokBase + r) * DIMS + c4 * 4) = v;
    }
#undef TILE
#undef LOADB
}

extern "C" void kernel_launch(void* const* d_in, const int* in_sizes, int n_in,
                              void* d_out, int out_size, void* d_ws, size_t ws_size,
                              hipStream_t stream) {
    const float* h  = (const float*)d_in[0];   // [32768, 256]
    const float* cb = (const float*)d_in[1];   // [8192, 256]
    float* out_q   = (float*)d_out;
    float* out_idx = (float*)d_out + (size_t)NTOK * DIMS;

    float* c2 = (float*)d_ws;                                       // 32 KB
    unsigned short* cbbf = (unsigned short*)((char*)d_ws + 32768);  // 4 MB, fragment-major
    const size_t needed = 32768 + (size_t)KCODES * DIMS * 2;
    const int wsbf = (ws_size >= needed) ? 1 : 0;

    prep_kernel<<<KCODES / 16 / 4, 256, 0, stream>>>(cb, c2, cbbf, wsbf);
    if (wsbf)
        vq_main<true><<<NTOK / BM, 512, 0, stream>>>(h, cb, cbbf, c2, out_q, out_idx);
    else
        vq_main<false><<<NTOK / BM, 512, 0, stream>>>(h, cb, (const unsigned short*)nullptr, c2, out_q, out_idx);
}